// Round 12
// baseline (317.468 us; speedup 1.0000x reference)
//
#include <hip/hip_runtime.h>
#include <hip/hip_fp16.h>
#include <cstdint>

#define N_NODES 100000
#define N_EDGES 3200000
#define BSZ     64                // dst nodes per bucket
#define NBUCK   1563              // ceil(N_NODES / 64)
#define NPAD    (NBUCK * BSZ)     // 100032
#define SORTCAP 4096              // bucket avg 2048, sigma ~45 -> huge margin
#define K13_BLOCKS 256
#define K13_CHUNK  12500          // 256 * 12500 = 3.2M exactly
#define K4_BLOCKS  2048
#define K5_BLOCKS  2048
#define K5_WAVES   (K5_BLOCKS * 4)
#define SRC_MID 50000             // src-group boundary: each group's h1 slice = 3.2 MB < 4 MB XCD L2

// ---- float <-> order-preserving unsigned (signed-float max via uint max) ----
__device__ __forceinline__ unsigned flipf(float f) {
    unsigned u = __float_as_uint(f);
    return (u & 0x80000000u) ? ~u : (u | 0x80000000u);   // never returns 0
}
__device__ __forceinline__ float unflipf(unsigned v) {
    unsigned u = (v & 0x80000000u) ? (v & 0x7FFFFFFFu) : ~v;
    return __uint_as_float(u);
}
__device__ __forceinline__ int2 nt_load_rec(const int2* p) {
    unsigned long long v = __builtin_nontemporal_load((const unsigned long long*)p);
    return make_int2((int)(unsigned)(v & 0xFFFFFFFFull), (int)(unsigned)(v >> 32));
}
__device__ __forceinline__ float cvt_h2f(unsigned u) {   // low 16 bits = fp16
    float r;
    asm("v_cvt_f32_f16 %0, %1" : "=v"(r) : "v"(u));
    return r;
}

// ---------------- K1: per-(block,bucket) counts, plain stores, NO global atomics ----------------
__global__ __launch_bounds__(1024) void k1_count(const int* __restrict__ dst,
                                                 int* __restrict__ cntMat) {
    __shared__ int hist[NBUCK];
    for (int t = threadIdx.x; t < NBUCK; t += 1024) hist[t] = 0;
    __syncthreads();
    int e0 = blockIdx.x * K13_CHUNK;
    for (int k = threadIdx.x; k < K13_CHUNK; k += 1024)
        atomicAdd(&hist[__builtin_nontemporal_load(&dst[e0 + k]) >> 6], 1);
    __syncthreads();
    int base = blockIdx.x * NBUCK;
    for (int t = threadIdx.x; t < NBUCK; t += 1024)
        cntMat[base + t] = hist[t];
}

// ---------------- K2a: bucket totals (coalesced, 1563-parallel) ----------------
__global__ __launch_bounds__(256) void k2a_totals(const int* __restrict__ cntMat,
                                                  int* __restrict__ total) {
    int t = blockIdx.x * 256 + threadIdx.x;
    if (t >= NBUCK) return;
    int s = 0;
    for (int b = 0; b < K13_BLOCKS; b++) s += cntMat[b * NBUCK + t];
    total[t] = s;
}

// ---------------- K2b: exclusive scan of 1563 totals -> bucketBase ----------------
__global__ __launch_bounds__(512) void k2b_scan(const int* __restrict__ total,
                                                int* __restrict__ bucketBase) {
    __shared__ int part[512];
    int t = threadIdx.x;
    int base = t * 4;
    int v0 = (base     < NBUCK) ? total[base]     : 0;
    int v1 = (base + 1 < NBUCK) ? total[base + 1] : 0;
    int v2 = (base + 2 < NBUCK) ? total[base + 2] : 0;
    int v3 = (base + 3 < NBUCK) ? total[base + 3] : 0;
    int s = v0 + v1 + v2 + v3;
    part[t] = s;
    __syncthreads();
    for (int off = 1; off < 512; off <<= 1) {
        int u = (t >= off) ? part[t - off] : 0;
        __syncthreads();
        part[t] += u;
        __syncthreads();
    }
    int ex = part[t] - s;
    if (base     < NBUCK) bucketBase[base]     = ex;
    if (base + 1 < NBUCK) bucketBase[base + 1] = ex + v0;
    if (base + 2 < NBUCK) bucketBase[base + 2] = ex + v0 + v1;
    if (base + 3 < NBUCK) bucketBase[base + 3] = ex + v0 + v1 + v2;
    if (t == 511) bucketBase[NBUCK] = part[511];
}

// ---------------- K2c: per-(block,bucket) bases (coalesced, 1563-parallel) ----------------
__global__ __launch_bounds__(256) void k2c_blockbase(const int* __restrict__ cntMat,
                                                     const int* __restrict__ bucketBase,
                                                     int* __restrict__ blockBase) {
    int t = blockIdx.x * 256 + threadIdx.x;
    if (t >= NBUCK) return;
    int run = bucketBase[t];
    for (int b = 0; b < K13_BLOCKS; b++) {
        blockBase[b * NBUCK + t] = run;
        run += cntMat[b * NBUCK + t];
    }
}

// ---------------- K3: LDS-PARTITIONED scatter -> contiguous per-(block,bucket) runs ----------------
// record: int2 { (src<<6) | (dst&63), bits(norm) }
__global__ __launch_bounds__(1024) void k3_scatter(const int* __restrict__ ei,
                                                   const float* __restrict__ norm,
                                                   const int* __restrict__ cntMat,
                                                   const int* __restrict__ blockBase,
                                                   int2* __restrict__ ebuf) {
    __shared__ int2 srecs[K13_CHUNK];        // 100 KB staging
    __shared__ int lbase[NBUCK];             // local exclusive scan
    __shared__ int lcur[NBUCK];
    __shared__ int part[1024];
    int t = threadIdx.x;
    int mrow = blockIdx.x * NBUCK;
    // local exclusive scan of this block's bucket counts (2 elems/thread, 2048 >= NBUCK)
    int i0 = 2 * t, i1 = 2 * t + 1;
    int v0 = (i0 < NBUCK) ? cntMat[mrow + i0] : 0;
    int v1 = (i1 < NBUCK) ? cntMat[mrow + i1] : 0;
    int s = v0 + v1;
    part[t] = s;
    __syncthreads();
    for (int off = 1; off < 1024; off <<= 1) {
        int u = (t >= off) ? part[t - off] : 0;
        __syncthreads();
        part[t] += u;
        __syncthreads();
    }
    int ex = part[t] - s;
    if (i0 < NBUCK) { lbase[i0] = ex;      lcur[i0] = ex; }
    if (i1 < NBUCK) { lbase[i1] = ex + v0; lcur[i1] = ex + v0; }
    __syncthreads();
    // partition chunk into LDS
    int e0 = blockIdx.x * K13_CHUNK;
    for (int k = t; k < K13_CHUNK; k += 1024) {
        int e = e0 + k;
        int sv = __builtin_nontemporal_load(&ei[e]);
        int d  = __builtin_nontemporal_load(&ei[N_EDGES + e]);
        float w = __builtin_nontemporal_load(&norm[e]);
        int r = atomicAdd(&lcur[d >> 6], 1);
        srecs[r] = make_int2((sv << 6) | (d & 63), __float_as_int(w));
    }
    __syncthreads();
    // write runs contiguously into global bucket regions
    for (int b = t; b < NBUCK; b += 1024) {
        int st = lbase[b], en = lcur[b];
        int gb = blockBase[mrow + b];
        for (int j = st; j < en; j++)
            ebuf[gb + (j - st)] = srecs[j];
    }
}

// ---- K3b: per-bucket counting sort with (dst-local, src-group) key, LDS-SORTED +
//      COALESCED write-back + FUSED layer-1 aggregation ----
//      Each node's records: group-0 (src<SRC_MID) first, then group-1; nodeMid = split.
//      128-bin offsets via PARALLEL scan (7 steps). Rewrites records as
//      { src*32 (element offset into h1 row), bits(norm) }.
__global__ __launch_bounds__(256) void k3b_sort_agg(
        const float2* __restrict__ x, const int* __restrict__ bucketBase,
        int2* __restrict__ ebuf, int* __restrict__ nodeBase, int* __restrict__ nodeMid,
        float* __restrict__ packed) {
    __shared__ int2 sorted[SORTCAP];         // 32 KB, only big LDS buffer
    __shared__ int cnt[BSZ * 2], offs[BSZ * 2], cur[BSZ * 2], sc[BSZ * 2];
    __shared__ float    s_a0[BSZ], s_a1[BSZ];
    __shared__ unsigned s_m0[BSZ], s_m1[BSZ];
    int b = blockIdx.x;
    int beg = bucketBase[b], end = bucketBase[b + 1];
    int n = end - beg;
    if (threadIdx.x < BSZ) {
        cnt[2 * threadIdx.x] = 0; cnt[2 * threadIdx.x + 1] = 0;
        s_a0[threadIdx.x] = 0.0f; s_a1[threadIdx.x] = 0.0f;
        s_m0[threadIdx.x] = 0u;   s_m1[threadIdx.x] = 0u;
    }
    __syncthreads();
    // pass 1: count (dst-local, group) bins + layer-1 aggregation
    for (int k = threadIdx.x; k < n; k += 256) {
        int2 r = ebuf[beg + k];
        int l = r.x & 63;
        int grp = ((r.x >> 6) >= SRC_MID) ? 1 : 0;
        atomicAdd(&cnt[(l << 1) | grp], 1);
        float2 xs = x[r.x >> 6];                 // 0.8 MB table, L2-resident
        float w = __int_as_float(r.y);
        atomicAdd(&s_a0[l], xs.x * w);
        atomicAdd(&s_a1[l], xs.y * w);
        atomicMax(&s_m0[l], flipf(xs.x));
        atomicMax(&s_m1[l], flipf(xs.y));
    }
    __syncthreads();
    // parallel exclusive scan of 128 bins (7 steps)
    {
        int t = threadIdx.x;
        if (t < BSZ * 2) sc[t] = cnt[t];
        __syncthreads();
        for (int off = 1; off < BSZ * 2; off <<= 1) {
            int u = (t >= off && t < BSZ * 2) ? sc[t - off] : 0;
            __syncthreads();
            if (t < BSZ * 2) sc[t] += u;
            __syncthreads();
        }
        if (t < BSZ * 2) { int ex = sc[t] - cnt[t]; offs[t] = ex; cur[t] = ex; }
        __syncthreads();
    }
    // pass 2: re-read (L2-hot) + scatter into LDS sorted[]
    for (int kk = beg + threadIdx.x; kk < end; kk += 256) {
        int2 r = nt_load_rec(&ebuf[kk]);
        int l = r.x & 63;
        int grp = ((r.x >> 6) >= SRC_MID) ? 1 : 0;
        int p = atomicAdd(&cur[(l << 1) | grp], 1);
        sorted[p] = make_int2((r.x >> 6) << 5, r.y);     // src*32 = h1 row elem offset
    }
    __syncthreads();
    // pass 3: coalesced contiguous write-back (keeps ebuf L2-resident for k5)
    for (int kk = threadIdx.x; kk < n; kk += 256)
        ebuf[beg + kk] = sorted[kk];

    if (threadIdx.x < BSZ) {
        nodeBase[b * BSZ + threadIdx.x] = beg + offs[2 * threadIdx.x];
        nodeMid [b * BSZ + threadIdx.x] = beg + offs[2 * threadIdx.x + 1];
    }
    if (threadIdx.x == BSZ) nodeBase[b * BSZ + BSZ] = end;  // benign same-value race
    __syncthreads();

    int t = threadIdx.x;
    if (t >= BSZ) return;
    int i = b * BSZ + t;
    if (i >= N_NODES) return;
    float2 xi = x[i];
    unsigned m0u = s_m0[t], m1u = s_m1[t];
    float m0 = m0u ? unflipf(m0u) : 0.0f;    // 0 sentinel == empty segment -> 0
    float m1 = m1u ? unflipf(m1u) : 0.0f;
    float4* pk = (float4*)(packed + ((size_t)i << 3));
    pk[0] = make_float4(xi.x, xi.y, s_a0[t], s_a1[t]);   // sub-row for f<24 lanes
    pk[1] = make_float4(xi.x, xi.y, m0, m1);             // sub-row for f>=24 lanes
}

// -------- K4: materialize layer-1 output h1[node][32] in FP16 (64 B/row) --------
__global__ __launch_bounds__(256) void k4_h1(
        const float* __restrict__ packed,
        const float* __restrict__ w1m_l, const float* __restrict__ b1m,
        const float* __restrict__ w1m_r,
        const float* __restrict__ w1x_l, const float* __restrict__ b1x,
        const float* __restrict__ w1x_r,
        __half* __restrict__ h1h) {
    int f = threadIdx.x & 31;
    float c0, c1, c2, c3, c4;
    if (f < 24) {
        c0 = b1m[f];
        c1 = w1m_l[2 * f]; c2 = w1m_l[2 * f + 1];
        c3 = w1m_r[2 * f]; c4 = w1m_r[2 * f + 1];
    } else {
        int g = f - 24;
        c0 = b1x[g];
        c1 = w1x_l[2 * g]; c2 = w1x_l[2 * g + 1];
        c3 = w1x_r[2 * g]; c4 = w1x_r[2 * g + 1];
    }
    int sel = (f < 24) ? 0 : 16;
    const char* pbase = (const char*)packed + sel;
    const int total = N_NODES * 32;
    // stride is a multiple of 32 -> f == idx&31 holds for every iteration
    for (int idx = blockIdx.x * 256 + threadIdx.x; idx < total; idx += K4_BLOCKS * 256) {
        int node = idx >> 5;
        float4 q = *(const float4*)(pbase + ((size_t)node << 5));
        h1h[idx] = __float2half(fmaxf(c0 + c3 * q.x + c4 * q.y + c1 * q.z + c2 * q.w, 0.0f));
    }
}

// -------- K5: layer-2 MAX+SUM, WAVE-per-node, SCALAR rec loads, SRC-GROUP PHASED --------
// Round-11 established: k5 is bound by the per-CU in-flight-line window (~40 lines) x
// gather latency (~430 cy mixed). Two stream-ordered passes, each gathering from a
// 3.2 MB h1 slice (< 4 MB XCD L2) -> L2-hit latency ~200 cy -> ~2x line service rate.
// Pass-merge is ONE coalesced o[lane] read: after the shfl combine, the h=0 lane
// needs exactly old mx[f] = o[lane] and the h=1 lane needs old sm[f] = o[lane].
// aggT traffic is nontemporal so it can't evict the h1 slice.
__global__ __launch_bounds__(256, 4) void k5_agg(
        const __half* __restrict__ h1h, const int2* __restrict__ ebuf,
        const int* __restrict__ nodeBase, const int* __restrict__ nodeMid,
        float* __restrict__ aggT, int pass) {
    int lane = threadIdx.x & 63;
    int f = lane & 31;
    int h = lane >> 5;                       // 0: even edges, 1: odd edges
    unsigned f2 = (unsigned)(f << 1);        // byte offset of this lane's fp16 feature
    int wid = blockIdx.x * 4 + (threadIdx.x >> 6);

    for (int i = wid; i < NPAD; i += K5_WAVES) {
        int e0, e1;
        if (pass == 0) {
            e0 = __builtin_amdgcn_readfirstlane(nodeBase[i]);
            e1 = __builtin_amdgcn_readfirstlane(nodeMid[i]);
        } else {
            e0 = __builtin_amdgcn_readfirstlane(nodeMid[i]);
            e1 = __builtin_amdgcn_readfirstlane(nodeBase[i + 1]);
        }
        float mx = 0.0f, sm = 0.0f;          // relu floor == empty-segment 0
        int e = e0;
        int nfull = (e1 - e0) >> 3;
        if (nfull > 0) {
            // int4 = 2 recs; 4 int4 = one 8-edge block. Uniform address -> s_load.
            const int4* rp = (const int4*)(ebuf + e0);
            int4 ra = rp[0], rb = rp[1], rc = rp[2], rd = rp[3];
            for (int blk = 1; blk < nfull; blk++) {
                const int4* np = (const int4*)(ebuf + e0 + blk * 8);
                int4 na = np[0], nb = np[1], nc = np[2], nd = np[3];
                unsigned o0 = ((unsigned)(h ? ra.z : ra.x) << 1) + f2;
                unsigned o1 = ((unsigned)(h ? rb.z : rb.x) << 1) + f2;
                unsigned o2 = ((unsigned)(h ? rc.z : rc.x) << 1) + f2;
                unsigned o3 = ((unsigned)(h ? rd.z : rd.x) << 1) + f2;
                float w0 = __int_as_float(h ? ra.w : ra.y);
                float w1 = __int_as_float(h ? rb.w : rb.y);
                float w2 = __int_as_float(h ? rc.w : rc.y);
                float w3 = __int_as_float(h ? rd.w : rd.y);
                unsigned u0, u1, u2, u3;
                asm volatile(
                    "global_load_ushort %0, %4, %8\n\t"
                    "global_load_ushort %1, %5, %8\n\t"
                    "global_load_ushort %2, %6, %8\n\t"
                    "global_load_ushort %3, %7, %8\n\t"
                    "s_waitcnt vmcnt(0)"
                    : "=&v"(u0), "=&v"(u1), "=&v"(u2), "=&v"(u3)
                    : "v"(o0), "v"(o1), "v"(o2), "v"(o3), "s"(h1h)
                    : "memory");
                float v0 = cvt_h2f(u0), v1 = cvt_h2f(u1);
                float v2 = cvt_h2f(u2), v3 = cvt_h2f(u3);
                mx = fmaxf(mx, v0); sm = fmaf(w0, v0, sm);
                mx = fmaxf(mx, v1); sm = fmaf(w1, v1, sm);
                mx = fmaxf(mx, v2); sm = fmaf(w2, v2, sm);
                mx = fmaxf(mx, v3); sm = fmaf(w3, v3, sm);
                ra = na; rb = nb; rc = nc; rd = nd;
            }
            {   // final prefetched block (already in ra..rd)
                unsigned o0 = ((unsigned)(h ? ra.z : ra.x) << 1) + f2;
                unsigned o1 = ((unsigned)(h ? rb.z : rb.x) << 1) + f2;
                unsigned o2 = ((unsigned)(h ? rc.z : rc.x) << 1) + f2;
                unsigned o3 = ((unsigned)(h ? rd.z : rd.x) << 1) + f2;
                float w0 = __int_as_float(h ? ra.w : ra.y);
                float w1 = __int_as_float(h ? rb.w : rb.y);
                float w2 = __int_as_float(h ? rc.w : rc.y);
                float w3 = __int_as_float(h ? rd.w : rd.y);
                unsigned u0, u1, u2, u3;
                asm volatile(
                    "global_load_ushort %0, %4, %8\n\t"
                    "global_load_ushort %1, %5, %8\n\t"
                    "global_load_ushort %2, %6, %8\n\t"
                    "global_load_ushort %3, %7, %8\n\t"
                    "s_waitcnt vmcnt(0)"
                    : "=&v"(u0), "=&v"(u1), "=&v"(u2), "=&v"(u3)
                    : "v"(o0), "v"(o1), "v"(o2), "v"(o3), "s"(h1h)
                    : "memory");
                float v0 = cvt_h2f(u0), v1 = cvt_h2f(u1);
                float v2 = cvt_h2f(u2), v3 = cvt_h2f(u3);
                mx = fmaxf(mx, v0); sm = fmaf(w0, v0, sm);
                mx = fmaxf(mx, v1); sm = fmaf(w1, v1, sm);
                mx = fmaxf(mx, v2); sm = fmaf(w2, v2, sm);
                mx = fmaxf(mx, v3); sm = fmaf(w3, v3, sm);
            }
            e = e0 + nfull * 8;
        }
        // tail: 2 edges per step (one per half)
        for (; e + 1 < e1; e += 2) {
            const int4* tp = (const int4*)(ebuf + e);
            int4 ta = tp[0];
            unsigned rx = (unsigned)(h ? ta.z : ta.x);
            float w = __int_as_float(h ? ta.w : ta.y);
            float v = __half2float(h1h[rx + (unsigned)f]);
            mx = fmaxf(mx, v); sm = fmaf(w, v, sm);
        }
        if (e < e1) {                        // one leftover edge, h=0 lanes only
            int2 r = ebuf[e];
            float v = __half2float(h1h[(unsigned)r.x + (unsigned)f]);
            if (h == 0) { mx = fmaxf(mx, v); sm = fmaf(__int_as_float(r.y), v, sm); }
        }
        // combine halves (each lane then holds the full result for feature f)
        sm += __shfl_xor(sm, 32);
        mx = fmaxf(mx, __shfl_xor(mx, 32));
        float* o = aggT + ((size_t)i << 6);
        float res;
        if (pass != 0) {
            float old = __builtin_nontemporal_load(&o[lane]);  // mx[f] for h=0, sm[f] for h=1
            res = h ? (sm + old) : fmaxf(mx, old);
        } else {
            res = h ? sm : mx;
        }
        __builtin_nontemporal_store(res, &o[lane]);  // one coalesced 256B store per node
    }
}

// -------- K6: node-parallel final: recompute hh (fp32-exact) + layer-2 + MLP head --------
__global__ __launch_bounds__(256) void k6_final(
        const float* __restrict__ packed, const float* __restrict__ aggT,
        const float* __restrict__ w1m_l, const float* __restrict__ b1m,
        const float* __restrict__ w1m_r,
        const float* __restrict__ w1x_l, const float* __restrict__ b1x,
        const float* __restrict__ w1x_r,
        const float* __restrict__ w2m_l,
        const float* __restrict__ b2m, const float* __restrict__ w2m_r,
        const float* __restrict__ w2x_l, const float* __restrict__ b2x,
        const float* __restrict__ w2x_r,
        const float* __restrict__ w3, const float* __restrict__ b3,
        const float* __restrict__ w4, const float* __restrict__ b4,
        const float* __restrict__ w5, const float* __restrict__ b5,
        float* __restrict__ out) {
    __shared__ float sw[1387];
    for (int t = threadIdx.x; t < 1387; t += 256) {
        float v;
        if (t < 48)        v = w1m_l[t];
        else if (t < 72)   v = b1m[t - 48];
        else if (t < 120)  v = w1m_r[t - 72];
        else if (t < 136)  v = w1x_l[t - 120];
        else if (t < 144)  v = b1x[t - 136];
        else if (t < 160)  v = w1x_r[t - 144];
        else if (t < 544)  v = w2m_l[t - 160];
        else if (t < 556)  v = b2m[t - 544];
        else if (t < 940)  v = w2m_r[t - 556];
        else if (t < 1068) v = w2x_l[t - 940];
        else if (t < 1072) v = b2x[t - 1068];
        else if (t < 1200) v = w2x_r[t - 1072];
        else if (t < 1328) v = w3[t - 1200];
        else if (t < 1336) v = b3[t - 1328];
        else if (t < 1376) v = w4[t - 1336];
        else if (t < 1381) v = b4[t - 1376];
        else if (t < 1386) v = w5[t - 1381];
        else               v = b5[0];
        sw[t] = v;
    }
    __syncthreads();

    int i = blockIdx.x * blockDim.x + threadIdx.x;
    if (i >= N_NODES) return;

    const float* row = packed + ((size_t)i << 3);
    float4 pf = *(const float4*)row;                     // x0,x1,a0,a1
    float2 pm = *(const float2*)(row + 6);               // m0,m1
    float xi0 = pf.x, xi1 = pf.y, a0 = pf.z, a1 = pf.w, m0 = pm.x, m1 = pm.y;

    float mxv[32], smv[32];
    const float4* at = (const float4*)(aggT + ((size_t)i << 6));
#pragma unroll
    for (int q = 0; q < 8; q++) {
        float4 a = at[q];
        mxv[4 * q] = a.x; mxv[4 * q + 1] = a.y; mxv[4 * q + 2] = a.z; mxv[4 * q + 3] = a.w;
        float4 s = at[8 + q];
        smv[4 * q] = s.x; smv[4 * q + 1] = s.y; smv[4 * q + 2] = s.z; smv[4 * q + 3] = s.w;
    }

    float hh[32];
#pragma unroll
    for (int k = 0; k < 24; k++) {
        float v = sw[48 + k] + sw[2 * k] * a0 + sw[2 * k + 1] * a1
                + sw[72 + 2 * k] * xi0 + sw[72 + 2 * k + 1] * xi1;
        hh[k] = fmaxf(v, 0.0f);
    }
#pragma unroll
    for (int k = 0; k < 8; k++) {
        float v = sw[136 + k] + sw[120 + 2 * k] * m0 + sw[120 + 2 * k + 1] * m1
                + sw[144 + 2 * k] * xi0 + sw[144 + 2 * k + 1] * xi1;
        hh[24 + k] = fmaxf(v, 0.0f);
    }

    float h2[16];
#pragma unroll
    for (int j = 0; j < 12; j++) {
        float v = sw[544 + j];
#pragma unroll
        for (int k = 0; k < 32; k++)
            v += smv[k] * sw[160 + j * 32 + k] + hh[k] * sw[556 + j * 32 + k];
        h2[j] = fmaxf(v, 0.0f);
    }
#pragma unroll
    for (int j = 0; j < 4; j++) {
        float v = sw[1068 + j];
#pragma unroll
        for (int k = 0; k < 32; k++)
            v += mxv[k] * sw[940 + j * 32 + k] + hh[k] * sw[1072 + j * 32 + k];
        h2[12 + j] = fmaxf(v, 0.0f);
    }

    float t3[8];
#pragma unroll
    for (int j = 0; j < 8; j++) {
        float v = sw[1328 + j];
#pragma unroll
        for (int k = 0; k < 16; k++) v += h2[k] * sw[1200 + j * 16 + k];
        t3[j] = fmaxf(v, 0.0f);
    }
    float t4[5];
#pragma unroll
    for (int j = 0; j < 5; j++) {
        float v = sw[1376 + j];
#pragma unroll
        for (int k = 0; k < 8; k++) v += t3[k] * sw[1336 + j * 8 + k];
        t4[j] = fmaxf(v, 0.0f);
    }
    float o = sw[1386];
#pragma unroll
    for (int k = 0; k < 5; k++) o += t4[k] * sw[1381 + k];
    out[i] = o;
}

extern "C" void kernel_launch(void* const* d_in, const int* in_sizes, int n_in,
                              void* d_out, int out_size, void* d_ws, size_t ws_size,
                              hipStream_t stream) {
    const float* x     = (const float*)d_in[0];
    const int*   ei    = (const int*)d_in[1];
    const float* norm  = (const float*)d_in[2];
    const float* w1m_l = (const float*)d_in[3];
    const float* b1m   = (const float*)d_in[4];
    const float* w1m_r = (const float*)d_in[5];
    const float* w1x_l = (const float*)d_in[6];
    const float* b1x   = (const float*)d_in[7];
    const float* w1x_r = (const float*)d_in[8];
    const float* w2m_l = (const float*)d_in[9];
    const float* b2m   = (const float*)d_in[10];
    const float* w2m_r = (const float*)d_in[11];
    const float* w2x_l = (const float*)d_in[12];
    const float* b2x   = (const float*)d_in[13];
    const float* w2x_r = (const float*)d_in[14];
    const float* w3    = (const float*)d_in[15];
    const float* b3    = (const float*)d_in[16];
    const float* w4    = (const float*)d_in[17];
    const float* b4    = (const float*)d_in[18];
    const float* w5    = (const float*)d_in[19];
    const float* b5    = (const float*)d_in[20];
    float* out = (float*)d_out;

    // workspace (~62 MB), every live buffer fully written -> no memsets
    char* ws = (char*)d_ws;
    int2*  ebuf   = (int2*)ws;                               // 25.6 MB
    float* packed = (float*)(ws + (size_t)N_EDGES * 8);      // NPAD*8*4  = 3.2 MB
    float* aggT   = packed + (size_t)NPAD * 8;               // NPAD*64*4 = 25.6 MB
    int*   nodeBase   = (int*)(aggT + (size_t)NPAD * 64);    // NPAD+1
    int*   nodeMid    = nodeBase + NPAD + 1;                 // NPAD
    int*   bucketBase = nodeMid + NPAD;                      // NBUCK+1
    int*   total      = bucketBase + NBUCK + 1;              // NBUCK
    // h1 (fp16): 64B-aligned, NPAD*32 halves = 6.4 MB
    size_t h1_off = (((size_t)(total + NBUCK) - (size_t)ws) + 63) & ~(size_t)63;
    __half* h1h = (__half*)(ws + h1_off);
    // cntMat/blockBase (3.2 MB, dead after k3_scatter) alias into h1's footprint (6.4 MB)
    int*   cntMat    = (int*)h1h;                            // 256*NBUCK = 1.6 MB
    int*   blockBase = cntMat + K13_BLOCKS * NBUCK;          // 256*NBUCK = 1.6 MB

    k1_count    <<<K13_BLOCKS, 1024, 0, stream>>>(ei + N_EDGES, cntMat);
    k2a_totals  <<<(NBUCK + 255) / 256, 256, 0, stream>>>(cntMat, total);
    k2b_scan    <<<1, 512, 0, stream>>>(total, bucketBase);
    k2c_blockbase<<<(NBUCK + 255) / 256, 256, 0, stream>>>(cntMat, bucketBase, blockBase);
    k3_scatter  <<<K13_BLOCKS, 1024, 0, stream>>>(ei, norm, cntMat, blockBase, ebuf);
    k3b_sort_agg<<<NBUCK, 256, 0, stream>>>((const float2*)x, bucketBase, ebuf,
                                            nodeBase, nodeMid, packed);
    k4_h1       <<<K4_BLOCKS, 256, 0, stream>>>(packed,
                                                w1m_l, b1m, w1m_r, w1x_l, b1x, w1x_r,
                                                h1h);
    k5_agg      <<<K5_BLOCKS, 256, 0, stream>>>(h1h, ebuf, nodeBase, nodeMid, aggT, 0);
    k5_agg      <<<K5_BLOCKS, 256, 0, stream>>>(h1h, ebuf, nodeBase, nodeMid, aggT, 1);
    k6_final    <<<(N_NODES + 255) / 256, 256, 0, stream>>>(packed, aggT,
                                                w1m_l, b1m, w1m_r, w1x_l, b1x, w1x_r,
                                                w2m_l, b2m, w2m_r, w2x_l, b2x, w2x_r,
                                                w3, b3, w4, b4, w5, b5, out);
}

// Round 13
// 289.523 us; speedup vs baseline: 1.0965x; 1.0965x over previous
//
#include <hip/hip_runtime.h>
#include <hip/hip_fp16.h>
#include <cstdint>

#define N_NODES 100000
#define N_EDGES 3200000
#define BSZ     64                // dst nodes per bucket
#define NBUCK   1563              // ceil(N_NODES / 64)
#define NPAD    (NBUCK * BSZ)     // 100032
#define SORTCAP 4096              // bucket avg 2048, sigma ~45 -> huge margin
#define K13_BLOCKS 256
#define K13_CHUNK  12500          // 256 * 12500 = 3.2M exactly
#define K5_BLOCKS  2048
#define K5_WAVES   (K5_BLOCKS * 4)

// ---- float <-> order-preserving unsigned (signed-float max via uint max) ----
__device__ __forceinline__ unsigned flipf(float f) {
    unsigned u = __float_as_uint(f);
    return (u & 0x80000000u) ? ~u : (u | 0x80000000u);   // never returns 0
}
__device__ __forceinline__ float unflipf(unsigned v) {
    unsigned u = (v & 0x80000000u) ? (v & 0x7FFFFFFFu) : ~v;
    return __uint_as_float(u);
}
__device__ __forceinline__ int2 nt_load_rec(const int2* p) {
    unsigned long long v = __builtin_nontemporal_load((const unsigned long long*)p);
    return make_int2((int)(unsigned)(v & 0xFFFFFFFFull), (int)(unsigned)(v >> 32));
}
__device__ __forceinline__ float cvt_h2f(unsigned u) {   // low 16 bits = fp16
    float r;
    asm("v_cvt_f32_f16 %0, %1" : "=v"(r) : "v"(u));
    return r;
}

// ---------------- K1: per-(block,bucket) counts, plain stores, NO global atomics ----------------
__global__ __launch_bounds__(1024) void k1_count(const int* __restrict__ dst,
                                                 int* __restrict__ cntMat) {
    __shared__ int hist[NBUCK];
    for (int t = threadIdx.x; t < NBUCK; t += 1024) hist[t] = 0;
    __syncthreads();
    int e0 = blockIdx.x * K13_CHUNK;
    for (int k = threadIdx.x; k < K13_CHUNK; k += 1024)
        atomicAdd(&hist[__builtin_nontemporal_load(&dst[e0 + k]) >> 6], 1);
    __syncthreads();
    int base = blockIdx.x * NBUCK;
    for (int t = threadIdx.x; t < NBUCK; t += 1024)
        cntMat[base + t] = hist[t];
}

// ---------------- K2a: bucket totals (coalesced, 1563-parallel) ----------------
__global__ __launch_bounds__(256) void k2a_totals(const int* __restrict__ cntMat,
                                                  int* __restrict__ total) {
    int t = blockIdx.x * 256 + threadIdx.x;
    if (t >= NBUCK) return;
    int s = 0;
    for (int b = 0; b < K13_BLOCKS; b++) s += cntMat[b * NBUCK + t];
    total[t] = s;
}

// ---------------- K2b: exclusive scan of 1563 totals -> bucketBase ----------------
__global__ __launch_bounds__(512) void k2b_scan(const int* __restrict__ total,
                                                int* __restrict__ bucketBase) {
    __shared__ int part[512];
    int t = threadIdx.x;
    int base = t * 4;
    int v0 = (base     < NBUCK) ? total[base]     : 0;
    int v1 = (base + 1 < NBUCK) ? total[base + 1] : 0;
    int v2 = (base + 2 < NBUCK) ? total[base + 2] : 0;
    int v3 = (base + 3 < NBUCK) ? total[base + 3] : 0;
    int s = v0 + v1 + v2 + v3;
    part[t] = s;
    __syncthreads();
    for (int off = 1; off < 512; off <<= 1) {
        int u = (t >= off) ? part[t - off] : 0;
        __syncthreads();
        part[t] += u;
        __syncthreads();
    }
    int ex = part[t] - s;
    if (base     < NBUCK) bucketBase[base]     = ex;
    if (base + 1 < NBUCK) bucketBase[base + 1] = ex + v0;
    if (base + 2 < NBUCK) bucketBase[base + 2] = ex + v0 + v1;
    if (base + 3 < NBUCK) bucketBase[base + 3] = ex + v0 + v1 + v2;
    if (t == 511) bucketBase[NBUCK] = part[511];
}

// ---------------- K2c: per-(block,bucket) bases (coalesced, 1563-parallel) ----------------
__global__ __launch_bounds__(256) void k2c_blockbase(const int* __restrict__ cntMat,
                                                     const int* __restrict__ bucketBase,
                                                     int* __restrict__ blockBase) {
    int t = blockIdx.x * 256 + threadIdx.x;
    if (t >= NBUCK) return;
    int run = bucketBase[t];
    for (int b = 0; b < K13_BLOCKS; b++) {
        blockBase[b * NBUCK + t] = run;
        run += cntMat[b * NBUCK + t];
    }
}

// ---------------- K3: LDS-PARTITIONED scatter -> contiguous per-(block,bucket) runs ----------------
// record: int2 { (src<<6) | (dst&63), bits(norm) }
__global__ __launch_bounds__(1024) void k3_scatter(const int* __restrict__ ei,
                                                   const float* __restrict__ norm,
                                                   const int* __restrict__ cntMat,
                                                   const int* __restrict__ blockBase,
                                                   int2* __restrict__ ebuf) {
    __shared__ int2 srecs[K13_CHUNK];        // 100 KB staging
    __shared__ int lbase[NBUCK];             // local exclusive scan
    __shared__ int lcur[NBUCK];
    __shared__ int part[1024];
    int t = threadIdx.x;
    int mrow = blockIdx.x * NBUCK;
    // local exclusive scan of this block's bucket counts (2 elems/thread, 2048 >= NBUCK)
    int i0 = 2 * t, i1 = 2 * t + 1;
    int v0 = (i0 < NBUCK) ? cntMat[mrow + i0] : 0;
    int v1 = (i1 < NBUCK) ? cntMat[mrow + i1] : 0;
    int s = v0 + v1;
    part[t] = s;
    __syncthreads();
    for (int off = 1; off < 1024; off <<= 1) {
        int u = (t >= off) ? part[t - off] : 0;
        __syncthreads();
        part[t] += u;
        __syncthreads();
    }
    int ex = part[t] - s;
    if (i0 < NBUCK) { lbase[i0] = ex;      lcur[i0] = ex; }
    if (i1 < NBUCK) { lbase[i1] = ex + v0; lcur[i1] = ex + v0; }
    __syncthreads();
    // partition chunk into LDS
    int e0 = blockIdx.x * K13_CHUNK;
    for (int k = t; k < K13_CHUNK; k += 1024) {
        int e = e0 + k;
        int sv = __builtin_nontemporal_load(&ei[e]);
        int d  = __builtin_nontemporal_load(&ei[N_EDGES + e]);
        float w = __builtin_nontemporal_load(&norm[e]);
        int r = atomicAdd(&lcur[d >> 6], 1);
        srecs[r] = make_int2((sv << 6) | (d & 63), __float_as_int(w));
    }
    __syncthreads();
    // write runs contiguously into global bucket regions
    for (int b = t; b < NBUCK; b += 1024) {
        int st = lbase[b], en = lcur[b];
        int gb = blockBase[mrow + b];
        for (int j = st; j < en; j++)
            ebuf[gb + (j - st)] = srecs[j];
    }
}

// ---- K3b: per-bucket counting sort, LDS-SORTED + COALESCED write-back (round-11 form)
//      + FUSED layer-1 aggregation -> packed row [x0,x1,a0,a1 | x0,x1,m0,m1] (32 B)
//      + FUSED k4: h1[node][32] fp16 computed in-block (k4 kernel deleted:
//        saves a launch + the packed->h1 HBM round trip). ----
__global__ __launch_bounds__(256) void k3b_sort_agg(
        const float2* __restrict__ x, const int* __restrict__ bucketBase,
        int2* __restrict__ ebuf, int* __restrict__ nodeBase,
        float* __restrict__ packed, __half* __restrict__ h1h,
        const float* __restrict__ w1m_l, const float* __restrict__ b1m,
        const float* __restrict__ w1m_r,
        const float* __restrict__ w1x_l, const float* __restrict__ b1x,
        const float* __restrict__ w1x_r) {
    __shared__ int2 sorted[SORTCAP];         // 32 KB, only big LDS buffer
    __shared__ int cnt[BSZ], off_s[BSZ], cur[BSZ], sc[BSZ];
    __shared__ float    s_a0[BSZ], s_a1[BSZ];
    __shared__ unsigned s_m0[BSZ], s_m1[BSZ];
    __shared__ float    s_x0[BSZ], s_x1[BSZ], s_um0[BSZ], s_um1[BSZ];
    int b = blockIdx.x;
    int beg = bucketBase[b], end = bucketBase[b + 1];
    int n = end - beg;
    if (threadIdx.x < BSZ) {
        cnt[threadIdx.x] = 0;
        s_a0[threadIdx.x] = 0.0f; s_a1[threadIdx.x] = 0.0f;
        s_m0[threadIdx.x] = 0u;   s_m1[threadIdx.x] = 0u;
    }
    __syncthreads();
    // pass 1: count + layer-1 aggregation (regular loads fill L2 for pass 2)
    for (int k = threadIdx.x; k < n; k += 256) {
        int2 r = ebuf[beg + k];
        int l = r.x & 63;
        atomicAdd(&cnt[l], 1);
        float2 xs = x[r.x >> 6];                 // 0.8 MB table, L2-resident
        float w = __int_as_float(r.y);
        atomicAdd(&s_a0[l], xs.x * w);
        atomicAdd(&s_a1[l], xs.y * w);
        atomicMax(&s_m0[l], flipf(xs.x));
        atomicMax(&s_m1[l], flipf(xs.y));
    }
    __syncthreads();
    // parallel exclusive scan of 64 bins (6 steps)
    {
        int t = threadIdx.x;
        if (t < BSZ) sc[t] = cnt[t];
        __syncthreads();
        for (int off = 1; off < BSZ; off <<= 1) {
            int u = (t >= off && t < BSZ) ? sc[t - off] : 0;
            __syncthreads();
            if (t < BSZ) sc[t] += u;
            __syncthreads();
        }
        if (t < BSZ) { int ex = sc[t] - cnt[t]; off_s[t] = ex; cur[t] = ex; }
        __syncthreads();
    }
    // pass 2: re-read (L2-hot) + scatter into LDS sorted[]
    for (int kk = beg + threadIdx.x; kk < end; kk += 256) {
        int2 r = nt_load_rec(&ebuf[kk]);
        int l = r.x & 63;
        int p = atomicAdd(&cur[l], 1);
        sorted[p] = make_int2((r.x >> 6) << 5, r.y);     // src*32 = h1 row elem offset
    }
    __syncthreads();
    // pass 3: coalesced contiguous write-back (keeps ebuf L2-resident for k5)
    for (int kk = threadIdx.x; kk < n; kk += 256)
        ebuf[beg + kk] = sorted[kk];

    if (threadIdx.x < BSZ) nodeBase[b * BSZ + threadIdx.x] = beg + off_s[threadIdx.x];
    if (threadIdx.x == BSZ) nodeBase[b * BSZ + BSZ] = end;  // benign same-value race

    // epilogue A (threads 0..63): packed row + stash per-node scalars for h1 compute
    {
        int t = threadIdx.x;
        int i = b * BSZ + t;
        if (t < BSZ && i < N_NODES) {
            float2 xi = x[i];
            unsigned m0u = s_m0[t], m1u = s_m1[t];
            float m0 = m0u ? unflipf(m0u) : 0.0f;    // 0 sentinel == empty segment -> 0
            float m1 = m1u ? unflipf(m1u) : 0.0f;
            s_x0[t] = xi.x; s_x1[t] = xi.y;
            s_um0[t] = m0;  s_um1[t] = m1;
            float4* pk = (float4*)(packed + ((size_t)i << 3));
            pk[0] = make_float4(xi.x, xi.y, s_a0[t], s_a1[t]);   // sub-row for f<24 lanes
            pk[1] = make_float4(xi.x, xi.y, m0, m1);             // sub-row for f>=24 lanes
        }
    }
    __syncthreads();

    // epilogue B (all 256 threads): fused k4 -> h1[node][f] fp16, coalesced 64B rows
    {
        int f = threadIdx.x & 31;
        float c0, c1, c2, c3, c4;
        if (f < 24) {
            c0 = b1m[f];
            c1 = w1m_l[2 * f]; c2 = w1m_l[2 * f + 1];
            c3 = w1m_r[2 * f]; c4 = w1m_r[2 * f + 1];
        } else {
            int g = f - 24;
            c0 = b1x[g];
            c1 = w1x_l[2 * g]; c2 = w1x_l[2 * g + 1];
            c3 = w1x_r[2 * g]; c4 = w1x_r[2 * g + 1];
        }
#pragma unroll
        for (int rep = 0; rep < 8; rep++) {
            int l = (threadIdx.x >> 5) + rep * 8;
            int node = b * BSZ + l;
            if (node < N_NODES) {
                float A, B;
                if (f < 24) { A = s_a0[l];  B = s_a1[l]; }
                else        { A = s_um0[l]; B = s_um1[l]; }
                float v = c0 + c3 * s_x0[l] + c4 * s_x1[l] + c1 * A + c2 * B;
                h1h[((size_t)node << 5) + f] = __float2half(fmaxf(v, 0.0f));
            }
        }
    }
}

// -------- K5: layer-2 MAX+SUM, WAVE-per-node, SCALAR rec loads (round-11 proven, 56.4 us) --------
// Lanes 0-31 = even edges, 32-63 = odd edges, feature f = lane&31. Records are
// wave-uniform -> s_load through the scalar cache (off the vector request path):
// 1 vector line-request per edge (the irreducible h1 gather). Halves combined via
// shfl_xor(32); one coalesced 256B store per node.
__global__ __launch_bounds__(256, 4) void k5_agg(
        const __half* __restrict__ h1h, const int2* __restrict__ ebuf,
        const int* __restrict__ nodeBase,
        float* __restrict__ aggT) {
    int lane = threadIdx.x & 63;
    int f = lane & 31;
    int h = lane >> 5;                       // 0: even edges, 1: odd edges
    unsigned f2 = (unsigned)(f << 1);        // byte offset of this lane's fp16 feature
    int wid = blockIdx.x * 4 + (threadIdx.x >> 6);

    for (int i = wid; i < NPAD; i += K5_WAVES) {
        int e0 = __builtin_amdgcn_readfirstlane(nodeBase[i]);
        int e1 = __builtin_amdgcn_readfirstlane(nodeBase[i + 1]);
        float mx = 0.0f, sm = 0.0f;          // relu floor == empty-segment 0
        int e = e0;
        int nfull = (e1 - e0) >> 3;
        if (nfull > 0) {
            // int4 = 2 recs; 4 int4 = one 8-edge block. Uniform address -> s_load.
            const int4* rp = (const int4*)(ebuf + e0);
            int4 ra = rp[0], rb = rp[1], rc = rp[2], rd = rp[3];
            for (int blk = 1; blk < nfull; blk++) {
                const int4* np = (const int4*)(ebuf + e0 + blk * 8);
                int4 na = np[0], nb = np[1], nc = np[2], nd = np[3];
                unsigned o0 = ((unsigned)(h ? ra.z : ra.x) << 1) + f2;
                unsigned o1 = ((unsigned)(h ? rb.z : rb.x) << 1) + f2;
                unsigned o2 = ((unsigned)(h ? rc.z : rc.x) << 1) + f2;
                unsigned o3 = ((unsigned)(h ? rd.z : rd.x) << 1) + f2;
                float w0 = __int_as_float(h ? ra.w : ra.y);
                float w1 = __int_as_float(h ? rb.w : rb.y);
                float w2 = __int_as_float(h ? rc.w : rc.y);
                float w3 = __int_as_float(h ? rd.w : rd.y);
                unsigned u0, u1, u2, u3;
                asm volatile(
                    "global_load_ushort %0, %4, %8\n\t"
                    "global_load_ushort %1, %5, %8\n\t"
                    "global_load_ushort %2, %6, %8\n\t"
                    "global_load_ushort %3, %7, %8\n\t"
                    "s_waitcnt vmcnt(0)"
                    : "=&v"(u0), "=&v"(u1), "=&v"(u2), "=&v"(u3)
                    : "v"(o0), "v"(o1), "v"(o2), "v"(o3), "s"(h1h)
                    : "memory");
                float v0 = cvt_h2f(u0), v1 = cvt_h2f(u1);
                float v2 = cvt_h2f(u2), v3 = cvt_h2f(u3);
                mx = fmaxf(mx, v0); sm = fmaf(w0, v0, sm);
                mx = fmaxf(mx, v1); sm = fmaf(w1, v1, sm);
                mx = fmaxf(mx, v2); sm = fmaf(w2, v2, sm);
                mx = fmaxf(mx, v3); sm = fmaf(w3, v3, sm);
                ra = na; rb = nb; rc = nc; rd = nd;
            }
            {   // final prefetched block (already in ra..rd)
                unsigned o0 = ((unsigned)(h ? ra.z : ra.x) << 1) + f2;
                unsigned o1 = ((unsigned)(h ? rb.z : rb.x) << 1) + f2;
                unsigned o2 = ((unsigned)(h ? rc.z : rc.x) << 1) + f2;
                unsigned o3 = ((unsigned)(h ? rd.z : rd.x) << 1) + f2;
                float w0 = __int_as_float(h ? ra.w : ra.y);
                float w1 = __int_as_float(h ? rb.w : rb.y);
                float w2 = __int_as_float(h ? rc.w : rc.y);
                float w3 = __int_as_float(h ? rd.w : rd.y);
                unsigned u0, u1, u2, u3;
                asm volatile(
                    "global_load_ushort %0, %4, %8\n\t"
                    "global_load_ushort %1, %5, %8\n\t"
                    "global_load_ushort %2, %6, %8\n\t"
                    "global_load_ushort %3, %7, %8\n\t"
                    "s_waitcnt vmcnt(0)"
                    : "=&v"(u0), "=&v"(u1), "=&v"(u2), "=&v"(u3)
                    : "v"(o0), "v"(o1), "v"(o2), "v"(o3), "s"(h1h)
                    : "memory");
                float v0 = cvt_h2f(u0), v1 = cvt_h2f(u1);
                float v2 = cvt_h2f(u2), v3 = cvt_h2f(u3);
                mx = fmaxf(mx, v0); sm = fmaf(w0, v0, sm);
                mx = fmaxf(mx, v1); sm = fmaf(w1, v1, sm);
                mx = fmaxf(mx, v2); sm = fmaf(w2, v2, sm);
                mx = fmaxf(mx, v3); sm = fmaf(w3, v3, sm);
            }
            e = e0 + nfull * 8;
        }
        // tail: 2 edges per step (one per half)
        for (; e + 1 < e1; e += 2) {
            const int4* tp = (const int4*)(ebuf + e);
            int4 ta = tp[0];
            unsigned rx = (unsigned)(h ? ta.z : ta.x);
            float w = __int_as_float(h ? ta.w : ta.y);
            float v = __half2float(h1h[rx + (unsigned)f]);
            mx = fmaxf(mx, v); sm = fmaf(w, v, sm);
        }
        if (e < e1) {                        // one leftover edge, h=0 lanes only
            int2 r = ebuf[e];
            float v = __half2float(h1h[(unsigned)r.x + (unsigned)f]);
            if (h == 0) { mx = fmaxf(mx, v); sm = fmaf(__int_as_float(r.y), v, sm); }
        }
        // combine halves (each lane then holds the full result for feature f)
        sm += __shfl_xor(sm, 32);
        mx = fmaxf(mx, __shfl_xor(mx, 32));
        float* o = aggT + ((size_t)i << 6);
        o[lane] = h ? sm : mx;               // one coalesced 256B store per node
    }
}

// -------- K6: node-parallel final: recompute hh (fp32-exact) + layer-2 + MLP head --------
__global__ __launch_bounds__(256) void k6_final(
        const float* __restrict__ packed, const float* __restrict__ aggT,
        const float* __restrict__ w1m_l, const float* __restrict__ b1m,
        const float* __restrict__ w1m_r,
        const float* __restrict__ w1x_l, const float* __restrict__ b1x,
        const float* __restrict__ w1x_r,
        const float* __restrict__ w2m_l,
        const float* __restrict__ b2m, const float* __restrict__ w2m_r,
        const float* __restrict__ w2x_l, const float* __restrict__ b2x,
        const float* __restrict__ w2x_r,
        const float* __restrict__ w3, const float* __restrict__ b3,
        const float* __restrict__ w4, const float* __restrict__ b4,
        const float* __restrict__ w5, const float* __restrict__ b5,
        float* __restrict__ out) {
    __shared__ float sw[1387];
    for (int t = threadIdx.x; t < 1387; t += 256) {
        float v;
        if (t < 48)        v = w1m_l[t];
        else if (t < 72)   v = b1m[t - 48];
        else if (t < 120)  v = w1m_r[t - 72];
        else if (t < 136)  v = w1x_l[t - 120];
        else if (t < 144)  v = b1x[t - 136];
        else if (t < 160)  v = w1x_r[t - 144];
        else if (t < 544)  v = w2m_l[t - 160];
        else if (t < 556)  v = b2m[t - 544];
        else if (t < 940)  v = w2m_r[t - 556];
        else if (t < 1068) v = w2x_l[t - 940];
        else if (t < 1072) v = b2x[t - 1068];
        else if (t < 1200) v = w2x_r[t - 1072];
        else if (t < 1328) v = w3[t - 1200];
        else if (t < 1336) v = b3[t - 1328];
        else if (t < 1376) v = w4[t - 1336];
        else if (t < 1381) v = b4[t - 1376];
        else if (t < 1386) v = w5[t - 1381];
        else               v = b5[0];
        sw[t] = v;
    }
    __syncthreads();

    int i = blockIdx.x * blockDim.x + threadIdx.x;
    if (i >= N_NODES) return;

    const float* row = packed + ((size_t)i << 3);
    float4 pf = *(const float4*)row;                     // x0,x1,a0,a1
    float2 pm = *(const float2*)(row + 6);               // m0,m1
    float xi0 = pf.x, xi1 = pf.y, a0 = pf.z, a1 = pf.w, m0 = pm.x, m1 = pm.y;

    float mxv[32], smv[32];
    const float4* at = (const float4*)(aggT + ((size_t)i << 6));
#pragma unroll
    for (int q = 0; q < 8; q++) {
        float4 a = at[q];
        mxv[4 * q] = a.x; mxv[4 * q + 1] = a.y; mxv[4 * q + 2] = a.z; mxv[4 * q + 3] = a.w;
        float4 s = at[8 + q];
        smv[4 * q] = s.x; smv[4 * q + 1] = s.y; smv[4 * q + 2] = s.z; smv[4 * q + 3] = s.w;
    }

    float hh[32];
#pragma unroll
    for (int k = 0; k < 24; k++) {
        float v = sw[48 + k] + sw[2 * k] * a0 + sw[2 * k + 1] * a1
                + sw[72 + 2 * k] * xi0 + sw[72 + 2 * k + 1] * xi1;
        hh[k] = fmaxf(v, 0.0f);
    }
#pragma unroll
    for (int k = 0; k < 8; k++) {
        float v = sw[136 + k] + sw[120 + 2 * k] * m0 + sw[120 + 2 * k + 1] * m1
                + sw[144 + 2 * k] * xi0 + sw[144 + 2 * k + 1] * xi1;
        hh[24 + k] = fmaxf(v, 0.0f);
    }

    float h2[16];
#pragma unroll
    for (int j = 0; j < 12; j++) {
        float v = sw[544 + j];
#pragma unroll
        for (int k = 0; k < 32; k++)
            v += smv[k] * sw[160 + j * 32 + k] + hh[k] * sw[556 + j * 32 + k];
        h2[j] = fmaxf(v, 0.0f);
    }
#pragma unroll
    for (int j = 0; j < 4; j++) {
        float v = sw[1068 + j];
#pragma unroll
        for (int k = 0; k < 32; k++)
            v += mxv[k] * sw[940 + j * 32 + k] + hh[k] * sw[1072 + j * 32 + k];
        h2[12 + j] = fmaxf(v, 0.0f);
    }

    float t3[8];
#pragma unroll
    for (int j = 0; j < 8; j++) {
        float v = sw[1328 + j];
#pragma unroll
        for (int k = 0; k < 16; k++) v += h2[k] * sw[1200 + j * 16 + k];
        t3[j] = fmaxf(v, 0.0f);
    }
    float t4[5];
#pragma unroll
    for (int j = 0; j < 5; j++) {
        float v = sw[1376 + j];
#pragma unroll
        for (int k = 0; k < 8; k++) v += t3[k] * sw[1336 + j * 8 + k];
        t4[j] = fmaxf(v, 0.0f);
    }
    float o = sw[1386];
#pragma unroll
    for (int k = 0; k < 5; k++) o += t4[k] * sw[1381 + k];
    out[i] = o;
}

extern "C" void kernel_launch(void* const* d_in, const int* in_sizes, int n_in,
                              void* d_out, int out_size, void* d_ws, size_t ws_size,
                              hipStream_t stream) {
    const float* x     = (const float*)d_in[0];
    const int*   ei    = (const int*)d_in[1];
    const float* norm  = (const float*)d_in[2];
    const float* w1m_l = (const float*)d_in[3];
    const float* b1m   = (const float*)d_in[4];
    const float* w1m_r = (const float*)d_in[5];
    const float* w1x_l = (const float*)d_in[6];
    const float* b1x   = (const float*)d_in[7];
    const float* w1x_r = (const float*)d_in[8];
    const float* w2m_l = (const float*)d_in[9];
    const float* b2m   = (const float*)d_in[10];
    const float* w2m_r = (const float*)d_in[11];
    const float* w2x_l = (const float*)d_in[12];
    const float* b2x   = (const float*)d_in[13];
    const float* w2x_r = (const float*)d_in[14];
    const float* w3    = (const float*)d_in[15];
    const float* b3    = (const float*)d_in[16];
    const float* w4    = (const float*)d_in[17];
    const float* b4    = (const float*)d_in[18];
    const float* w5    = (const float*)d_in[19];
    const float* b5    = (const float*)d_in[20];
    float* out = (float*)d_out;

    // workspace (~61 MB), every live buffer fully written -> no memsets
    char* ws = (char*)d_ws;
    int2*  ebuf   = (int2*)ws;                               // 25.6 MB
    float* packed = (float*)(ws + (size_t)N_EDGES * 8);      // NPAD*8*4  = 3.2 MB
    float* aggT   = packed + (size_t)NPAD * 8;               // NPAD*64*4 = 25.6 MB
    int*   nodeBase   = (int*)(aggT + (size_t)NPAD * 64);    // NPAD+1
    int*   bucketBase = nodeBase + NPAD + 1;                 // NBUCK+1
    int*   total      = bucketBase + NBUCK + 1;              // NBUCK
    // h1 (fp16): 64B-aligned, NPAD*32 halves = 6.4 MB
    size_t h1_off = (((size_t)(total + NBUCK) - (size_t)ws) + 63) & ~(size_t)63;
    __half* h1h = (__half*)(ws + h1_off);
    // cntMat/blockBase (3.2 MB, dead after k3_scatter) alias into h1's footprint (6.4 MB)
    int*   cntMat    = (int*)h1h;                            // 256*NBUCK = 1.6 MB
    int*   blockBase = cntMat + K13_BLOCKS * NBUCK;          // 256*NBUCK = 1.6 MB

    k1_count    <<<K13_BLOCKS, 1024, 0, stream>>>(ei + N_EDGES, cntMat);
    k2a_totals  <<<(NBUCK + 255) / 256, 256, 0, stream>>>(cntMat, total);
    k2b_scan    <<<1, 512, 0, stream>>>(total, bucketBase);
    k2c_blockbase<<<(NBUCK + 255) / 256, 256, 0, stream>>>(cntMat, bucketBase, blockBase);
    k3_scatter  <<<K13_BLOCKS, 1024, 0, stream>>>(ei, norm, cntMat, blockBase, ebuf);
    k3b_sort_agg<<<NBUCK, 256, 0, stream>>>((const float2*)x, bucketBase, ebuf,
                                            nodeBase, packed, h1h,
                                            w1m_l, b1m, w1m_r, w1x_l, b1x, w1x_r);
    k5_agg      <<<K5_BLOCKS, 256, 0, stream>>>(h1h, ebuf, nodeBase, aggT);
    k6_final    <<<(N_NODES + 255) / 256, 256, 0, stream>>>(packed, aggT,
                                                w1m_l, b1m, w1m_r, w1x_l, b1x, w1x_r,
                                                w2m_l, b2m, w2m_r, w2x_l, b2x, w2x_r,
                                                w3, b3, w4, b4, w5, b5, out);
}